// Round 10
// baseline (255.420 us; speedup 1.0000x reference)
//
#include <hip/hip_runtime.h>

typedef unsigned short u16;
typedef unsigned int u32;
typedef unsigned long long u64;
typedef __bf16 bf16x8 __attribute__((ext_vector_type(8)));
typedef float f32x4 __attribute__((ext_vector_type(4)));
typedef u16 u16x8 __attribute__((ext_vector_type(8)));

#define C_DIM 512
#define N_TOK 4096
#define HEADS 8
#define K3 1536
// 8 * log2(e): folds the *8 logit scale and the exp->exp2 conversion into Q.
#define QSCALE 11.5415603071f

// async global->LDS DMA, 16B per lane; LDS dest = wave-uniform base + lane*16.
#define GLDS(SRC, DST)                                                        \
  __builtin_amdgcn_global_load_lds(                                           \
      (const __attribute__((address_space(1))) void*)(SRC),                   \
      (__attribute__((address_space(3))) void*)(DST), 16, 0, 0)

__device__ __forceinline__ u16 f2bf(float f) {
  u32 u = __builtin_bit_cast(u32, f);
  u += 0x7FFFu + ((u >> 16) & 1u);
  return (u16)(u >> 16);
}
__device__ __forceinline__ float bf2f(u16 b) {
  u32 u = ((u32)b) << 16;
  return __builtin_bit_cast(float, u);
}

// w_qkv [1536][512] f32 -> A1 [1536][1536] bf16 cols = [hi | hi | lo]
__global__ void prep_w_kernel(const float* __restrict__ w, u16* __restrict__ A1) {
  int i = blockIdx.x * 256 + threadIdx.x;
  if (i >= 1536 * 512) return;
  int m = i >> 9, c = i & 511;
  float v = w[i];
  u16 hi = f2bf(v);
  u16 lo = f2bf(v - bf2f(hi));
  u16* row = A1 + (size_t)m * K3;
  row[c] = hi; row[512 + c] = hi; row[1024 + c] = lo;
}

// w_out [512][512] f32 -> bf16
__global__ void prep_wout_kernel(const float* __restrict__ w, u16* __restrict__ A2) {
  int i = blockIdx.x * 256 + threadIdx.x;
  if (i >= 512 * 512) return;
  A2[i] = f2bf(w[i]);
}

// x [512][4096] f32 -> B1 [4096][1536] bf16 cols = [xhi | xlo | xhi] (transpose via LDS)
__global__ __launch_bounds__(256) void prep_x_kernel(const float* __restrict__ x, u16* __restrict__ B1) {
  __shared__ float lds[64][65];
  int n0 = blockIdx.x * 64, c0 = blockIdx.y * 64;
  int tid = threadIdx.x;
#pragma unroll
  for (int i = 0; i < 4; i++) {
    int idx = tid + i * 256;
    int r = idx >> 4, s = idx & 15;
    const float4 v = *(const float4*)(x + (size_t)(c0 + r) * N_TOK + n0 + s * 4);
    lds[r][s * 4 + 0] = v.x; lds[r][s * 4 + 1] = v.y;
    lds[r][s * 4 + 2] = v.z; lds[r][s * 4 + 3] = v.w;
  }
  __syncthreads();
  int n = tid >> 2, cs = tid & 3;
  u16x8 hv[2], lv[2];
#pragma unroll
  for (int half2 = 0; half2 < 2; half2++) {
#pragma unroll
    for (int j = 0; j < 8; j++) {
      float v = lds[cs * 16 + half2 * 8 + j][n];
      u16 hi = f2bf(v);
      hv[half2][j] = hi;
      lv[half2][j] = f2bf(v - bf2f(hi));
    }
  }
  u16* row = B1 + (size_t)(n0 + n) * K3 + c0 + cs * 16;
  *(u16x8*)(row) = hv[0];
  *(u16x8*)(row + 8) = hv[1];
  *(u16x8*)(row + 512) = lv[0];
  *(u16x8*)(row + 520) = lv[1];
  *(u16x8*)(row + 1024) = hv[0];
  *(u16x8*)(row + 1032) = hv[1];
}

// NT GEMM: C[m][n] = sum_k A[m][k]*B[n][k]; 128x128 tile, BK=64, 4 waves, swizzled LDS.
__global__ __launch_bounds__(256) void gemm_nt_kernel(
    const u16* __restrict__ A, const u16* __restrict__ B, float* __restrict__ C,
    int M, int N, int K) {
  __shared__ char lds[128 * 64 * 2 * 2];
  char* ldsA = lds;
  char* ldsB = lds + 128 * 64 * 2;
  int n0 = blockIdx.x * 128, m0 = blockIdx.y * 128;
  int tid = threadIdx.x, lane = tid & 63, wid = tid >> 6;
  int wr = wid >> 1, wc = wid & 1;
  f32x4 acc[4][4] = {};
  for (int k0 = 0; k0 < K; k0 += 64) {
    __syncthreads();
#pragma unroll
    for (int i = 0; i < 4; i++) {
      int idx = tid + i * 256;
      int row = idx >> 3, cb = idx & 7;
      uint4 va = *(const uint4*)(A + (size_t)(m0 + row) * K + k0 + cb * 8);
      *(uint4*)(ldsA + row * 128 + ((cb * 16) ^ ((row & 7) << 4))) = va;
      uint4 vb = *(const uint4*)(B + (size_t)(n0 + row) * K + k0 + cb * 8);
      *(uint4*)(ldsB + row * 128 + ((cb * 16) ^ ((row & 7) << 4))) = vb;
    }
    __syncthreads();
#pragma unroll
    for (int kk = 0; kk < 2; kk++) {
      bf16x8 af[4], bfr[4];
#pragma unroll
      for (int mt = 0; mt < 4; mt++) {
        int row = wr * 64 + mt * 16 + (lane & 15);
        int kb = kk * 64 + ((lane >> 4) << 4);
        af[mt] = *(const bf16x8*)(ldsA + row * 128 + (kb ^ ((row & 7) << 4)));
      }
#pragma unroll
      for (int nt = 0; nt < 4; nt++) {
        int row = wc * 64 + nt * 16 + (lane & 15);
        int kb = kk * 64 + ((lane >> 4) << 4);
        bfr[nt] = *(const bf16x8*)(ldsB + row * 128 + (kb ^ ((row & 7) << 4)));
      }
#pragma unroll
      for (int mt = 0; mt < 4; mt++)
#pragma unroll
        for (int nt = 0; nt < 4; nt++)
          acc[mt][nt] = __builtin_amdgcn_mfma_f32_16x16x32_bf16(af[mt], bfr[nt], acc[mt][nt], 0, 0, 0);
    }
  }
#pragma unroll
  for (int mt = 0; mt < 4; mt++)
#pragma unroll
    for (int nt = 0; nt < 4; nt++) {
      int row = m0 + wr * 64 + mt * 16 + ((lane >> 4) << 2);
      int col = n0 + wc * 64 + nt * 16 + (lane & 15);
#pragma unroll
      for (int r = 0; r < 4; r++)
        C[(size_t)(row + r) * N + col] = acc[mt][nt][r];
    }
}

// qkv [4096][1536] f32 -> Qp [8][4096][128] bf16 [hi|lo] (Q pre-scaled by 8*log2e)
//                      -> Kimg [8][64 tiles][16KB LDS image] (pre-swizzled for DMA)
// Image formula MUST match attn's K-read: byte = row*256 + ((cb*16) ^ ((row&7)<<4)),
// chunk cb = dh>>3 for hi, 8+(dh>>3) for lo; element j = dh&7.
__global__ void prep_qk_kernel(const float* __restrict__ qkv, u16* __restrict__ Qp, u16* __restrict__ Kimg) {
  int i = blockIdx.x * 256 + threadIdx.x;  // 8*4096*64 = 2097152 exact
  int dh = i & 63;
  int n = (i >> 6) & 4095;
  int h = i >> 18;
  float q = qkv[(size_t)n * K3 + h * 64 + dh] * QSCALE;
  float k = qkv[(size_t)n * K3 + 512 + h * 64 + dh];
  u16 qhi = f2bf(q); u16 qlo = f2bf(q - bf2f(qhi));
  u16 khi = f2bf(k); u16 klo = f2bf(k - bf2f(khi));
  u16* qr = Qp + ((size_t)h * N_TOK + n) * 128;
  qr[dh] = qhi; qr[64 + dh] = qlo;
  u16* kt = Kimg + ((size_t)h * 64 + (n >> 6)) * 8192;  // 16KB tile = 8192 u16
  int row = n & 63;
  int swz = (row & 7) << 4;
  int bh = row * 256 + (((dh >> 3) * 16) ^ swz);
  int bl = row * 256 + ((((dh >> 3) + 8) * 16) ^ swz);
  kt[(bh >> 1) + (dh & 7)] = khi;
  kt[(bl >> 1) + (dh & 7)] = klo;
}

// qkv V-part -> Vimg [8][64 tiles][8KB LDS image] (V^T, pre-swizzled for DMA).
// Image formula matches attn's V-read: byte = row*128 + ((cb*16) ^ ((row&7)<<4)),
// row = dh, cb = kv_in_tile>>3, content V[tile*64 + cb*8 + j][dh].
__global__ __launch_bounds__(256) void prep_v_kernel(const float* __restrict__ qkv, u16* __restrict__ Vimg) {
  __shared__ float lds[64][65];
  int tile = blockIdx.x, h = blockIdx.y;
  int n0 = tile * 64;
  int tid = threadIdx.x;
#pragma unroll
  for (int i = 0; i < 4; i++) {
    int idx = tid + i * 256;
    int r = idx >> 4, s = idx & 15;
    const float4 v = *(const float4*)(qkv + (size_t)(n0 + r) * K3 + 1024 + h * 64 + s * 4);
    lds[r][s * 4 + 0] = v.x; lds[r][s * 4 + 1] = v.y;
    lds[r][s * 4 + 2] = v.z; lds[r][s * 4 + 3] = v.w;
  }
  __syncthreads();
  int dh = tid >> 2, ns = tid & 3;
  u16* vt = Vimg + ((size_t)h * 64 + tile) * 4096;  // 8KB tile = 4096 u16
#pragma unroll
  for (int half2 = 0; half2 < 2; half2++) {
    u16x8 pv;
#pragma unroll
    for (int j = 0; j < 8; j++)
      pv[j] = f2bf(lds[ns * 16 + half2 * 8 + j][dh]);
    int cb = ns * 2 + half2;
    int off = dh * 64 + ((((cb * 16) ^ ((dh & 7) << 4))) >> 1);
    *(u16x8*)(vt + off) = pv;
  }
}

// Flash attention, KV-split=2, swapped QK^T, glds 2-phase double-buffered pipeline.
// Block = (64 q-rows, head, kv-half); 4 waves; 32 kv tiles of 64; 1 barrier/iter.
// LDS: K0 @0, K1 @16384 (16KB each); V0 @32768, V1 @40960 (8KB each); P @49152 (8KB).
__global__ __launch_bounds__(256) void attn_kernel(
    const u16* __restrict__ Qp, const u16* __restrict__ Kimg,
    const u16* __restrict__ Vimg, float* __restrict__ Uws,
    float* __restrict__ Mws, float* __restrict__ Lws) {
  __shared__ char lds[57344];
  int bid = blockIdx.x;
  int h = bid & 7;               // head -> XCD round-robin (confirmed L2 win)
  int rest = bid >> 3;
  int half = rest & 1;
  int q0 = (rest >> 1) * 64;
  int tid = threadIdx.x, lane = tid & 63, wid = tid >> 6;
  char* myP = lds + 49152 + wid * 2048;
  int qcol = lane & 15;
  int g = lane >> 4;

  // Q fragments (plain layout, unchanged)
  bf16x8 qf[4];
  {
    const u16* qrow = Qp + ((size_t)h * N_TOK + q0 + wid * 16 + qcol) * 128 + (g * 8);
#pragma unroll
    for (int c = 0; c < 4; c++) qf[c] = *(const bf16x8*)(qrow + c * 32);
  }

  // DMA source bases (advance by tile); lane*16 gives the per-lane 16B slice.
  const char* ksrc = (const char*)Kimg + ((size_t)h * 64 + half * 32) * 16384 + wid * 1024 + lane * 16;
  const char* vsrc = (const char*)Vimg + ((size_t)h * 64 + half * 32) * 8192 + wid * 1024 + lane * 16;

  // Loop-invariant LDS read/write offsets (hoisted out of the hot loop).
  int koff[4][4];  // [nt][c]
  int voff[2][4];  // [c][nt]
  int poffw[4], poffr[2];
#pragma unroll
  for (int nt = 0; nt < 4; nt++) {
    int row = nt * 16 + qcol;
    int swz = (row & 7) << 4;
#pragma unroll
    for (int c = 0; c < 4; c++)
      koff[nt][c] = row * 256 + ((c * 64 + g * 16) ^ swz);
    int vrow = nt * 16 + qcol;
    int vswz = (vrow & 7) << 4;
#pragma unroll
    for (int c = 0; c < 2; c++)
      voff[c][nt] = vrow * 128 + ((c * 64 + g * 16) ^ vswz);
    poffw[nt] = qcol * 128 + ((nt * 32 + g * 8) ^ ((qcol & 7) << 4));
  }
#pragma unroll
  for (int c = 0; c < 2; c++)
    poffr[c] = qcol * 128 + ((c * 64 + g * 16) ^ ((qcol & 7) << 4));

  // Prologue: DMA tile 0 into buffer 0; __syncthreads drains vmcnt + syncs.
#pragma unroll
  for (int j = 0; j < 4; j++) GLDS(ksrc + j * 4096, lds + wid * 1024 + j * 4096);
#pragma unroll
  for (int j = 0; j < 2; j++) GLDS(vsrc + j * 4096, lds + 32768 + wid * 1024 + j * 4096);
  __syncthreads();

  f32x4 o[4] = {};
  float mrow = -INFINITY, lrow = 0.f;  // log2 domain
  int cur = 0;

  for (int t = 0; t < 32; ++t) {
    // Issue next tile's DMA into the back buffer (in flight during compute).
    if (t < 31) {
      const char* kn = ksrc + (size_t)(t + 1) * 16384;
      const char* vn = vsrc + (size_t)(t + 1) * 8192;
      char* kd = lds + (cur ^ 1) * 16384 + wid * 1024;
      char* vd = lds + 32768 + (cur ^ 1) * 8192 + wid * 1024;
#pragma unroll
      for (int j = 0; j < 4; j++) GLDS(kn + j * 4096, kd + j * 4096);
#pragma unroll
      for (int j = 0; j < 2; j++) GLDS(vn + j * 4096, vd + j * 4096);
    }
    const char* kbuf = lds + cur * 16384;
    const char* vbuf = lds + 32768 + cur * 8192;

    // S^T = mfma(K, Q): s[nt][r] = S[kv = nt*16 + g*4 + r][q = qcol], log2 domain.
    f32x4 s[4];
    __builtin_amdgcn_s_setprio(1);
#pragma unroll
    for (int nt = 0; nt < 4; nt++) {
      bf16x8 kf0 = *(const bf16x8*)(kbuf + koff[nt][0]);
      bf16x8 kf1 = *(const bf16x8*)(kbuf + koff[nt][1]);
      bf16x8 kf2 = *(const bf16x8*)(kbuf + koff[nt][2]);
      bf16x8 kf3 = *(const bf16x8*)(kbuf + koff[nt][3]);
      f32x4 acc = {};
      acc = __builtin_amdgcn_mfma_f32_16x16x32_bf16(kf0, qf[0], acc, 0, 0, 0);
      acc = __builtin_amdgcn_mfma_f32_16x16x32_bf16(kf1, qf[1], acc, 0, 0, 0);
      acc = __builtin_amdgcn_mfma_f32_16x16x32_bf16(kf2, qf[0], acc, 0, 0, 0);
      acc = __builtin_amdgcn_mfma_f32_16x16x32_bf16(kf3, qf[1], acc, 0, 0, 0);
      acc = __builtin_amdgcn_mfma_f32_16x16x32_bf16(kf0, qf[2], acc, 0, 0, 0);
      acc = __builtin_amdgcn_mfma_f32_16x16x32_bf16(kf1, qf[3], acc, 0, 0, 0);
      s[nt] = acc;
    }
    __builtin_amdgcn_s_setprio(0);

    // lane-local softmax (q = qcol): 16 in-register values, 2+2 shuffles.
    float m = s[0][0];
#pragma unroll
    for (int nt = 0; nt < 4; nt++)
#pragma unroll
      for (int r = 0; r < 4; r++) m = fmaxf(m, s[nt][r]);
    m = fmaxf(m, __shfl_xor(m, 16));
    m = fmaxf(m, __shfl_xor(m, 32));
    float mnew = fmaxf(mrow, m);
    float alpha = exp2f(mrow - mnew);
    mrow = mnew;
    float psum = 0.f;
#pragma unroll
    for (int nt = 0; nt < 4; nt++)
#pragma unroll
      for (int r = 0; r < 4; r++) {
        float p = exp2f(s[nt][r] - mnew);
        s[nt][r] = p;
        psum += p;
      }
    psum += __shfl_xor(psum, 16);
    psum += __shfl_xor(psum, 32);
    lrow = lrow * alpha + psum;

    // rescale O: o's q index is (g*4 + r) -> alpha from lane holding that q.
#pragma unroll
    for (int r = 0; r < 4; r++) {
      float a = __shfl(alpha, (g << 2) | r);
      o[0][r] *= a; o[1][r] *= a; o[2][r] *= a; o[3][r] *= a;
    }

    // P -> per-wave LDS (wave-private: no barrier; same-wave lgkm ordering).
#pragma unroll
    for (int nt = 0; nt < 4; nt++) {
      u16 h0 = f2bf(s[nt][0]), h1 = f2bf(s[nt][1]);
      u16 h2 = f2bf(s[nt][2]), h3 = f2bf(s[nt][3]);
      u32 w0 = (u32)h0 | ((u32)h1 << 16);
      u32 w1 = (u32)h2 | ((u32)h3 << 16);
      *(uint2*)(myP + poffw[nt]) = make_uint2(w0, w1);
    }

    // O += P . V
    __builtin_amdgcn_s_setprio(1);
#pragma unroll
    for (int c = 0; c < 2; c++) {
      bf16x8 pf = *(const bf16x8*)(myP + poffr[c]);
#pragma unroll
      for (int nt = 0; nt < 4; nt++) {
        bf16x8 vf = *(const bf16x8*)(vbuf + voff[c][nt]);
        o[nt] = __builtin_amdgcn_mfma_f32_16x16x32_bf16(pf, vf, o[nt], 0, 0, 0);
      }
    }
    __builtin_amdgcn_s_setprio(0);

    // One barrier per iter: drains vmcnt (next buffer complete) + syncs block.
    __syncthreads();
    cur ^= 1;
  }

  // epilogue: write unnormalized U (f32); o[nt][r] is q = g*4+r, dh = nt*16+(lane&15).
  size_t base = ((size_t)(half * HEADS + h) * N_TOK);
#pragma unroll
  for (int r = 0; r < 4; r++) {
    int tok = q0 + wid * 16 + (g << 2) + r;
    float* urow = Uws + (base + tok) * 64;
#pragma unroll
    for (int nt = 0; nt < 4; nt++)
      urow[nt * 16 + (lane & 15)] = o[nt][r];
  }
  // M/L: lane holds m/l for q = qcol; single writer per token (g==0 lanes).
  if (g == 0) {
    int tok = q0 + wid * 16 + qcol;
    Mws[base + tok] = mrow;
    Lws[base + tok] = lrow;
  }
}

// Combine the two KV-halves (log2 domain): w_i = exp2(m_i - m)
__global__ void reduce_kernel(const float* __restrict__ Uws, const float* __restrict__ Mws,
                              const float* __restrict__ Lws, u16* __restrict__ Obuf) {
  int i = blockIdx.x * 256 + threadIdx.x;  // 8*4096*16 = 524288 exact
  int d4 = i & 15;
  int tok = (i >> 4) & 4095;
  int h = i >> 16;
  size_t b1 = (size_t)h * N_TOK + tok;
  size_t b2 = (size_t)(HEADS + h) * N_TOK + tok;
  float m1 = Mws[b1], m2 = Mws[b2];
  float l1 = Lws[b1], l2 = Lws[b2];
  float m = fmaxf(m1, m2);
  float w1 = exp2f(m1 - m), w2 = exp2f(m2 - m);
  float inv = 1.0f / (l1 * w1 + l2 * w2);
  f32x4 u1 = *(const f32x4*)(Uws + b1 * 64 + d4 * 4);
  f32x4 u2 = *(const f32x4*)(Uws + b2 * 64 + d4 * 4);
  u16* dst = Obuf + (size_t)tok * C_DIM + h * 64 + d4 * 4;
#pragma unroll
  for (int j = 0; j < 4; j++)
    dst[j] = f2bf((u1[j] * w1 + u2[j] * w2) * inv);
}

extern "C" void kernel_launch(void* const* d_in, const int* in_sizes, int n_in,
                              void* d_out, int out_size, void* d_ws, size_t ws_size,
                              hipStream_t stream) {
  const float* x = (const float*)d_in[0];      // [512][4096]
  const float* w_qkv = (const float*)d_in[1];  // [1536][512]
  const float* w_out = (const float*)d_in[2];  // [512][512]
  float* out = (float*)d_out;                  // [512][4096]
  char* ws = (char*)d_ws;
  // Workspace (59,768,832 B total, proven available). Overlays:
  //   Obuf overlays B1; Vimg (4MB) overlays A1 (4.7MB); U/M/L overlay qkv;
  //   Kimg (8MB) lives in the old Kp slot (8.39MB).
  size_t off = 0;
  size_t off_B1 = off;  off += (size_t)N_TOK * K3 * 2;          // 12,582,912
  size_t off_A1 = off;  off += (size_t)K3 * K3 * 2;             //  4,718,592
  size_t off_A2 = off;  off += (size_t)512 * 512 * 2;           //    524,288
  size_t off_qkv = off; off += (size_t)N_TOK * K3 * 4;          // 25,165,824
  size_t off_Qp = off;  off += (size_t)HEADS * N_TOK * 128 * 2; //  8,388,608
  size_t off_Kp = off;  off += (size_t)HEADS * N_TOK * 128 * 2; //  8,388,608
  u16* B1 = (u16*)(ws + off_B1);
  u16* A1 = (u16*)(ws + off_A1);
  u16* A2 = (u16*)(ws + off_A2);
  float* qkv = (float*)(ws + off_qkv);
  u16* Qp = (u16*)(ws + off_Qp);
  u16* Kimg = (u16*)(ws + off_Kp);   // 8 * 64 * 16384 B = 8,388,608 exact
  u16* Vimg = (u16*)(ws + off_A1);   // 8 * 64 * 8192 B = 4,194,304 <= 4,718,592
  u16* Obuf = (u16*)(ws + off_B1);   // overlay B1
  float* Uws = (float*)(ws + off_qkv);                       // 16,777,216
  float* Mws = (float*)(ws + off_qkv + 16777216);            //    262,144
  float* Lws = (float*)(ws + off_qkv + 16777216 + 262144);   //    262,144

  prep_w_kernel<<<(1536 * 512 + 255) / 256, 256, 0, stream>>>(w_qkv, A1);
  prep_wout_kernel<<<(512 * 512 + 255) / 256, 256, 0, stream>>>(w_out, A2);
  prep_x_kernel<<<dim3(64, 8), 256, 0, stream>>>(x, B1);
  gemm_nt_kernel<<<dim3(K3 / 128, N_TOK / 128), 256, 0, stream>>>(B1, A1, qkv, N_TOK, K3, K3);
  prep_qk_kernel<<<(HEADS * N_TOK * 64) / 256, 256, 0, stream>>>(qkv, Qp, Kimg);
  prep_v_kernel<<<dim3(64, 8), 256, 0, stream>>>(qkv, Vimg);
  attn_kernel<<<1024, 256, 0, stream>>>(Qp, Kimg, Vimg, Uws, Mws, Lws);
  reduce_kernel<<<(HEADS * N_TOK * 16) / 256, 256, 0, stream>>>(Uws, Mws, Lws, Obuf);
  gemm_nt_kernel<<<dim3(N_TOK / 128, 512 / 128), 256, 0, stream>>>(A2, Obuf, out, 512, N_TOK, 512);
}

// Round 11
// 223.272 us; speedup vs baseline: 1.1440x; 1.1440x over previous
//
#include <hip/hip_runtime.h>

typedef unsigned short u16;
typedef unsigned int u32;
typedef __bf16 bf16x8 __attribute__((ext_vector_type(8)));
typedef __bf16 bf16x4 __attribute__((ext_vector_type(4)));
typedef float f32x4 __attribute__((ext_vector_type(4)));
typedef u16 u16x8 __attribute__((ext_vector_type(8)));

#define C_DIM 512
#define N_TOK 4096
#define HEADS 8
#define K3 1536
// 8 * log2(e): folds the *8 logit scale and exp->exp2 into Q.
#define QSCALE 11.5415603071f

// async global->LDS DMA, 16B/lane; HW adds lane*16 to the uniform LDS base.
#define GLDS(SRC, DST)                                                        \
  __builtin_amdgcn_global_load_lds(                                           \
      (const __attribute__((address_space(1))) void*)(SRC),                   \
      (__attribute__((address_space(3))) void*)(DST), 16, 0, 0)

__device__ __forceinline__ u16 f2bf(float f) {
  u32 u = __builtin_bit_cast(u32, f);
  u += 0x7FFFu + ((u >> 16) & 1u);
  return (u16)(u >> 16);
}
__device__ __forceinline__ float bf2f(u16 b) {
  u32 u = ((u32)b) << 16;
  return __builtin_bit_cast(float, u);
}
__device__ __forceinline__ float fast_exp2(float x) {
  float r;
  asm("v_exp_f32 %0, %1" : "=v"(r) : "v"(x));
  return r;
}

// w_qkv [1536][512] f32 -> A1img: B-operand tile images [12 nblk][24 kblk][16KB],
// logical cols = [Whi(512) | Whi | Wlo]. Tile byte layout == gemm's LDS layout:
// byte = rr*128 + ((cb*16) ^ ((rr&7)<<4)) + elem*2, rr=row&127, cb=(k&63)>>3.
__global__ void prep_w_kernel(const float* __restrict__ w, u16* __restrict__ A1img) {
  int i = blockIdx.x * 256 + threadIdx.x;
  if (i >= 1536 * 512) return;
  int m = i >> 9, c = i & 511;
  float v = w[i];
  u16 hi = f2bf(v);
  u16 lo = f2bf(v - bf2f(hi));
  int rr = m & 127, mb = m >> 7;
  int kc = c & 63, kb0 = c >> 6;
  int idx = (rr * 128 + (((kc >> 3) * 16) ^ ((rr & 7) << 4))) / 2 + (kc & 7);
  A1img[((size_t)(mb * 24 + kb0)) * 8192 + idx] = hi;
  A1img[((size_t)(mb * 24 + 8 + kb0)) * 8192 + idx] = hi;
  A1img[((size_t)(mb * 24 + 16 + kb0)) * 8192 + idx] = lo;
}

// w_out [512][512] f32 -> bf16 (gemm2 stays reg-staged, linear)
__global__ void prep_wout_kernel(const float* __restrict__ w, u16* __restrict__ A2) {
  int i = blockIdx.x * 256 + threadIdx.x;
  if (i >= 512 * 512) return;
  A2[i] = f2bf(w[i]);
}

// x [512][4096] f32 -> B1img: A-operand tile images [32 mblk][24 kblk][16KB],
// logical cols = [xhi | xlo | xhi]. Same tile byte layout as prep_w.
__global__ __launch_bounds__(256) void prep_x_kernel(const float* __restrict__ x, u16* __restrict__ B1img) {
  __shared__ float lds[64][65];
  int n0 = blockIdx.x * 64, c0 = blockIdx.y * 64;
  int tid = threadIdx.x;
#pragma unroll
  for (int i = 0; i < 4; i++) {
    int idx = tid + i * 256;
    int r = idx >> 4, s = idx & 15;
    const float4 v = *(const float4*)(x + (size_t)(c0 + r) * N_TOK + n0 + s * 4);
    lds[r][s * 4 + 0] = v.x; lds[r][s * 4 + 1] = v.y;
    lds[r][s * 4 + 2] = v.z; lds[r][s * 4 + 3] = v.w;
  }
  __syncthreads();
  int n = n0 + (tid >> 2), cs = tid & 3;
  int rr = n & 127, nb = n >> 7;
  int kb0 = c0 >> 6;
#pragma unroll
  for (int half2 = 0; half2 < 2; half2++) {
    u16x8 hv, lv;
#pragma unroll
    for (int j = 0; j < 8; j++) {
      float v = lds[cs * 16 + half2 * 8 + j][(tid >> 2)];
      u16 hi = f2bf(v);
      hv[j] = hi;
      lv[j] = f2bf(v - bf2f(hi));
    }
    int kc = cs * 16 + half2 * 8;  // within k-block, 8-aligned
    int idx = (rr * 128 + (((kc >> 3) * 16) ^ ((rr & 7) << 4))) / 2;
    *(u16x8*)(B1img + ((size_t)(nb * 24 + kb0)) * 8192 + idx) = hv;       // xhi
    *(u16x8*)(B1img + ((size_t)(nb * 24 + 8 + kb0)) * 8192 + idx) = lv;   // xlo
    *(u16x8*)(B1img + ((size_t)(nb * 24 + 16 + kb0)) * 8192 + idx) = hv;  // xhi
  }
}

// GLDS-staged NT GEMM over pre-swizzled tile images (m97 structure).
// C[m][n] = sum_k A[m][k]*B[n][k]; 128x128 tile, BK=64, 4 waves.
__global__ __launch_bounds__(256) void gemm_img_kernel(
    const u16* __restrict__ Aimg, const u16* __restrict__ Bimg,
    float* __restrict__ C, int M, int N, int K) {
  __shared__ char lds[32768];
  char* ldsA = lds;
  char* ldsB = lds + 16384;
  int n0 = blockIdx.x * 128, m0 = blockIdx.y * 128;
  int nKb = K >> 6;
  int tid = threadIdx.x, lane = tid & 63, wid = tid >> 6;
  int wr = wid >> 1, wc = wid & 1;
  const char* Abase = (const char*)Aimg + (size_t)blockIdx.y * nKb * 16384 + wid * 4096 + lane * 16;
  const char* Bbase = (const char*)Bimg + (size_t)blockIdx.x * nKb * 16384 + wid * 4096 + lane * 16;
  char* ldsAw = ldsA + wid * 4096;
  char* ldsBw = ldsB + wid * 4096;
  f32x4 acc[4][4] = {};
  for (int kt = 0; kt < nKb; kt++) {
    __syncthreads();  // prior compute's LDS reads done
    const char* a = Abase + (size_t)kt * 16384;
    const char* b = Bbase + (size_t)kt * 16384;
#pragma unroll
    for (int j = 0; j < 4; j++) GLDS(a + j * 1024, ldsAw + j * 1024);
#pragma unroll
    for (int j = 0; j < 4; j++) GLDS(b + j * 1024, ldsBw + j * 1024);
    __syncthreads();  // drains vmcnt: tiles landed
#pragma unroll
    for (int kk = 0; kk < 2; kk++) {
      bf16x8 af[4], bfr[4];
#pragma unroll
      for (int mt = 0; mt < 4; mt++) {
        int row = wr * 64 + mt * 16 + (lane & 15);
        int kb = kk * 64 + ((lane >> 4) << 4);
        af[mt] = *(const bf16x8*)(ldsA + row * 128 + (kb ^ ((row & 7) << 4)));
      }
#pragma unroll
      for (int nt = 0; nt < 4; nt++) {
        int row = wc * 64 + nt * 16 + (lane & 15);
        int kb = kk * 64 + ((lane >> 4) << 4);
        bfr[nt] = *(const bf16x8*)(ldsB + row * 128 + (kb ^ ((row & 7) << 4)));
      }
#pragma unroll
      for (int mt = 0; mt < 4; mt++)
#pragma unroll
        for (int nt = 0; nt < 4; nt++)
          acc[mt][nt] = __builtin_amdgcn_mfma_f32_16x16x32_bf16(af[mt], bfr[nt], acc[mt][nt], 0, 0, 0);
    }
  }
#pragma unroll
  for (int mt = 0; mt < 4; mt++)
#pragma unroll
    for (int nt = 0; nt < 4; nt++) {
      int row = m0 + wr * 64 + mt * 16 + ((lane >> 4) << 2);
      int col = n0 + wc * 64 + nt * 16 + (lane & 15);
#pragma unroll
      for (int r = 0; r < 4; r++)
        C[(size_t)(row + r) * N + col] = acc[mt][nt][r];
    }
}

// Reg-staged NT GEMM (proven; used for gemm2 with linear A2/Obuf).
__global__ __launch_bounds__(256) void gemm_nt_kernel(
    const u16* __restrict__ A, const u16* __restrict__ B, float* __restrict__ C,
    int M, int N, int K) {
  __shared__ char lds[128 * 64 * 2 * 2];
  char* ldsA = lds;
  char* ldsB = lds + 128 * 64 * 2;
  int n0 = blockIdx.x * 128, m0 = blockIdx.y * 128;
  int tid = threadIdx.x, lane = tid & 63, wid = tid >> 6;
  int wr = wid >> 1, wc = wid & 1;
  f32x4 acc[4][4] = {};
  for (int k0 = 0; k0 < K; k0 += 64) {
    __syncthreads();
#pragma unroll
    for (int i = 0; i < 4; i++) {
      int idx = tid + i * 256;
      int row = idx >> 3, cb = idx & 7;
      uint4 va = *(const uint4*)(A + (size_t)(m0 + row) * K + k0 + cb * 8);
      *(uint4*)(ldsA + row * 128 + ((cb * 16) ^ ((row & 7) << 4))) = va;
      uint4 vb = *(const uint4*)(B + (size_t)(n0 + row) * K + k0 + cb * 8);
      *(uint4*)(ldsB + row * 128 + ((cb * 16) ^ ((row & 7) << 4))) = vb;
    }
    __syncthreads();
#pragma unroll
    for (int kk = 0; kk < 2; kk++) {
      bf16x8 af[4], bfr[4];
#pragma unroll
      for (int mt = 0; mt < 4; mt++) {
        int row = wr * 64 + mt * 16 + (lane & 15);
        int kb = kk * 64 + ((lane >> 4) << 4);
        af[mt] = *(const bf16x8*)(ldsA + row * 128 + (kb ^ ((row & 7) << 4)));
      }
#pragma unroll
      for (int nt = 0; nt < 4; nt++) {
        int row = wc * 64 + nt * 16 + (lane & 15);
        int kb = kk * 64 + ((lane >> 4) << 4);
        bfr[nt] = *(const bf16x8*)(ldsB + row * 128 + (kb ^ ((row & 7) << 4)));
      }
#pragma unroll
      for (int mt = 0; mt < 4; mt++)
#pragma unroll
        for (int nt = 0; nt < 4; nt++)
          acc[mt][nt] = __builtin_amdgcn_mfma_f32_16x16x32_bf16(af[mt], bfr[nt], acc[mt][nt], 0, 0, 0);
    }
  }
#pragma unroll
  for (int mt = 0; mt < 4; mt++)
#pragma unroll
    for (int nt = 0; nt < 4; nt++) {
      int row = m0 + wr * 64 + mt * 16 + ((lane >> 4) << 2);
      int col = n0 + wc * 64 + nt * 16 + (lane & 15);
#pragma unroll
      for (int r = 0; r < 4; r++)
        C[(size_t)(row + r) * N + col] = acc[mt][nt][r];
    }
}

// qkv [4096][1536] f32 -> Qp/Kp [8][4096][128] bf16, both [hi | lo].
// Q pre-scaled by 8*log2(e) -> exp2 domain logits. (r8-proven linear layout.)
__global__ void prep_qk_kernel(const float* __restrict__ qkv, u16* __restrict__ Qp, u16* __restrict__ Kp) {
  int i = blockIdx.x * 256 + threadIdx.x;  // 8*4096*64 exact
  int dh = i & 63;
  int n = (i >> 6) & 4095;
  int h = i >> 18;
  float q = qkv[(size_t)n * K3 + h * 64 + dh] * QSCALE;
  float k = qkv[(size_t)n * K3 + 512 + h * 64 + dh];
  u16 qhi = f2bf(q); u16 qlo = f2bf(q - bf2f(qhi));
  u16 khi = f2bf(k); u16 klo = f2bf(k - bf2f(khi));
  u16* qr = Qp + ((size_t)h * N_TOK + n) * 128;
  u16* kr = Kp + ((size_t)h * N_TOK + n) * 128;
  qr[dh] = qhi; qr[64 + dh] = qlo;
  kr[dh] = khi; kr[64 + dh] = klo;
}

// qkv V-part -> Vt [8][64][4096] bf16 (V^T per head; r8-proven linear layout)
__global__ __launch_bounds__(256) void prep_v_kernel(const float* __restrict__ qkv, u16* __restrict__ Vt) {
  __shared__ float lds[64][65];
  int n0 = blockIdx.x * 64, h = blockIdx.y;
  int tid = threadIdx.x;
#pragma unroll
  for (int i = 0; i < 4; i++) {
    int idx = tid + i * 256;
    int r = idx >> 4, s = idx & 15;
    const float4 v = *(const float4*)(qkv + (size_t)(n0 + r) * K3 + 1024 + h * 64 + s * 4);
    lds[r][s * 4 + 0] = v.x; lds[r][s * 4 + 1] = v.y;
    lds[r][s * 4 + 2] = v.z; lds[r][s * 4 + 3] = v.w;
  }
  __syncthreads();
  int dh = tid >> 2, ns = tid & 3;
  u16x8 pv[2];
#pragma unroll
  for (int half2 = 0; half2 < 2; half2++)
#pragma unroll
    for (int j = 0; j < 8; j++)
      pv[half2][j] = f2bf(lds[ns * 16 + half2 * 8 + j][dh]);
  u16* dst = Vt + ((size_t)h * 64 + dh) * N_TOK + n0 + ns * 16;
  *(u16x8*)(dst) = pv[0];
  *(u16x8*)(dst + 8) = pv[1];
}

// Flash attention, KV-split=2, swapped QK^T (r8-proven 2-barrier structure)
// + native cvt_pk P-pack + raw v_exp + defer-max + setprio.
// Block = (64 q-rows, head, kv-half); 4 waves; 32 kv tiles of 64.
// LDS: K 16KB @0; V 8KB @16384; P 8KB @24576 (per-wave).
__global__ __launch_bounds__(256) void attn_kernel(
    const u16* __restrict__ Qp, const u16* __restrict__ Kp,
    const u16* __restrict__ Vt, float* __restrict__ Uws,
    float* __restrict__ Mws, float* __restrict__ Lws) {
  __shared__ char lds[32768];
  char* ldsK = lds;
  char* ldsV = lds + 16384;
  char* ldsP = lds + 24576;
  int bid = blockIdx.x;
  int h = bid & 7;               // head -> XCD round-robin (proven L2 win)
  int rest = bid >> 3;
  int half = rest & 1;
  int q0 = (rest >> 1) * 64;
  int kvbase = half * 2048;
  int tid = threadIdx.x, lane = tid & 63, wid = tid >> 6;
  char* myP = ldsP + wid * 2048;
  int qcol = lane & 15;
  int g = lane >> 4;

  bf16x8 qf[4];
  {
    const u16* qrow = Qp + ((size_t)h * N_TOK + q0 + wid * 16 + qcol) * 128 + (g * 8);
#pragma unroll
    for (int c = 0; c < 4; c++) qf[c] = *(const bf16x8*)(qrow + c * 32);
  }
  const u16* Kbase = Kp + (size_t)h * N_TOK * 128;
  const u16* Vbase = Vt + (size_t)h * 64 * N_TOK;

  f32x4 o[4] = {};
  float mrow = -INFINITY, lrow = 0.f;  // log2 domain

  for (int t = 0; t < 32; ++t) {
    int kv0 = kvbase + t * 64;
    __syncthreads();  // prior iter's LDS reads done
#pragma unroll
    for (int i = 0; i < 4; i++) {
      int idx = tid + i * 256, row = idx >> 4, cb = idx & 15;
      uint4 v = *(const uint4*)(Kbase + (size_t)(kv0 + row) * 128 + cb * 8);
      *(uint4*)(ldsK + row * 256 + ((cb * 16) ^ ((row & 7) << 4))) = v;
    }
#pragma unroll
    for (int i = 0; i < 2; i++) {
      int idx = tid + i * 256, row = idx >> 3, cb = idx & 7;
      uint4 v = *(const uint4*)(Vbase + (size_t)row * N_TOK + kv0 + cb * 8);
      *(uint4*)(ldsV + row * 128 + ((cb * 16) ^ ((row & 7) << 4))) = v;
    }
    __syncthreads();  // panels ready

    // S^T = mfma(K, Q): s[nt][r] = S[kv=nt*16+g*4+r][q=qcol], log2 domain.
    f32x4 s[4];
    __builtin_amdgcn_s_setprio(1);
#pragma unroll
    for (int nt = 0; nt < 4; nt++) {
      int row = nt * 16 + qcol;
      const char* kb = ldsK + row * 256;
      int swz = (row & 7) << 4;
      int ko = g << 4;
      bf16x8 kf0 = *(const bf16x8*)(kb + ((ko) ^ swz));
      bf16x8 kf1 = *(const bf16x8*)(kb + ((64 + ko) ^ swz));
      bf16x8 kf2 = *(const bf16x8*)(kb + ((128 + ko) ^ swz));
      bf16x8 kf3 = *(const bf16x8*)(kb + ((192 + ko) ^ swz));
      f32x4 acc = {};
      acc = __builtin_amdgcn_mfma_f32_16x16x32_bf16(kf0, qf[0], acc, 0, 0, 0);
      acc = __builtin_amdgcn_mfma_f32_16x16x32_bf16(kf1, qf[1], acc, 0, 0, 0);
      acc = __builtin_amdgcn_mfma_f32_16x16x32_bf16(kf2, qf[0], acc, 0, 0, 0);
      acc = __builtin_amdgcn_mfma_f32_16x16x32_bf16(kf3, qf[1], acc, 0, 0, 0);
      acc = __builtin_amdgcn_mfma_f32_16x16x32_bf16(kf0, qf[2], acc, 0, 0, 0);
      acc = __builtin_amdgcn_mfma_f32_16x16x32_bf16(kf1, qf[3], acc, 0, 0, 0);
      s[nt] = acc;
    }
    __builtin_amdgcn_s_setprio(0);

    // lane-local softmax (q = qcol), defer-max (T13, THR=12 log2-units).
    float m = s[0][0];
#pragma unroll
    for (int nt = 0; nt < 4; nt++)
#pragma unroll
      for (int r = 0; r < 4; r++) m = fmaxf(m, s[nt][r]);
    m = fmaxf(m, __shfl_xor(m, 16));
    m = fmaxf(m, __shfl_xor(m, 32));
    if (!__all(m - mrow <= 12.0f)) {
      float mnew = fmaxf(mrow, m);
      float alpha = fast_exp2(mrow - mnew);
      mrow = mnew;
      lrow *= alpha;
#pragma unroll
      for (int r = 0; r < 4; r++) {
        float a = __shfl(alpha, (g << 2) | r);
        o[0][r] *= a; o[1][r] *= a; o[2][r] *= a; o[3][r] *= a;
      }
    }
    float psum = 0.f;
#pragma unroll
    for (int nt = 0; nt < 4; nt++)
#pragma unroll
      for (int r = 0; r < 4; r++) {
        float p = fast_exp2(s[nt][r] - mrow);
        s[nt][r] = p;
        psum += p;
      }
    psum += __shfl_xor(psum, 16);
    psum += __shfl_xor(psum, 32);
    lrow += psum;

    // P -> per-wave LDS via native bf16 casts (compiler emits v_cvt_pk_bf16_f32).
#pragma unroll
    for (int nt = 0; nt < 4; nt++) {
      bf16x4 pb;
      pb[0] = (__bf16)s[nt][0]; pb[1] = (__bf16)s[nt][1];
      pb[2] = (__bf16)s[nt][2]; pb[3] = (__bf16)s[nt][3];
      int off = (nt * 32 + g * 8) ^ ((qcol & 7) << 4);
      *(bf16x4*)(myP + qcol * 128 + off) = pb;
    }
    // No barrier: myP wave-private; same-wave LDS ordering via lgkmcnt.

    // O += P . V
    __builtin_amdgcn_s_setprio(1);
#pragma unroll
    for (int c = 0; c < 2; c++) {
      int prow = lane & 15;
      int kb2 = c * 64 + (g << 4);
      bf16x8 pf = *(const bf16x8*)(myP + prow * 128 + (kb2 ^ ((prow & 7) << 4)));
#pragma unroll
      for (int nt = 0; nt < 4; nt++) {
        int vrow = nt * 16 + (lane & 15);
        bf16x8 vf = *(const bf16x8*)(ldsV + vrow * 128 + (kb2 ^ ((vrow & 7) << 4)));
        o[nt] = __builtin_amdgcn_mfma_f32_16x16x32_bf16(pf, vf, o[nt], 0, 0, 0);
      }
    }
    __builtin_amdgcn_s_setprio(0);
  }

  // epilogue: unnormalized U (f32); o[nt][r] is q=g*4+r, dh=nt*16+(lane&15).
  size_t base = ((size_t)(half * HEADS + h) * N_TOK);
#pragma unroll
  for (int r = 0; r < 4; r++) {
    int tok = q0 + wid * 16 + (g << 2) + r;
    float* urow = Uws + (base + tok) * 64;
#pragma unroll
    for (int nt = 0; nt < 4; nt++)
      urow[nt * 16 + (lane & 15)] = o[nt][r];
  }
  if (g == 0) {
    int tok = q0 + wid * 16 + qcol;
    Mws[base + tok] = mrow;
    Lws[base + tok] = lrow;
  }
}

// Combine the two KV-halves (log2 domain): w_i = exp2(m_i - m)
__global__ void reduce_kernel(const float* __restrict__ Uws, const float* __restrict__ Mws,
                              const float* __restrict__ Lws, u16* __restrict__ Obuf) {
  int i = blockIdx.x * 256 + threadIdx.x;  // 8*4096*16 exact
  int d4 = i & 15;
  int tok = (i >> 4) & 4095;
  int h = i >> 16;
  size_t b1 = (size_t)h * N_TOK + tok;
  size_t b2 = (size_t)(HEADS + h) * N_TOK + tok;
  float m1 = Mws[b1], m2 = Mws[b2];
  float l1 = Lws[b1], l2 = Lws[b2];
  float m = fmaxf(m1, m2);
  float w1 = exp2f(m1 - m), w2 = exp2f(m2 - m);
  float inv = 1.0f / (l1 * w1 + l2 * w2);
  f32x4 u1 = *(const f32x4*)(Uws + b1 * 64 + d4 * 4);
  f32x4 u2 = *(const f32x4*)(Uws + b2 * 64 + d4 * 4);
  u16* dst = Obuf + (size_t)tok * C_DIM + h * 64 + d4 * 4;
#pragma unroll
  for (int j = 0; j < 4; j++)
    dst[j] = f2bf((u1[j] * w1 + u2[j] * w2) * inv);
}

extern "C" void kernel_launch(void* const* d_in, const int* in_sizes, int n_in,
                              void* d_out, int out_size, void* d_ws, size_t ws_size,
                              hipStream_t stream) {
  const float* x = (const float*)d_in[0];      // [512][4096]
  const float* w_qkv = (const float*)d_in[1];  // [1536][512]
  const float* w_out = (const float*)d_in[2];  // [512][512]
  float* out = (float*)d_out;                  // [512][4096]
  char* ws = (char*)d_ws;
  // Workspace (59,768,832 B, proven). Image sizes equal the old slots:
  // B1img 12,582,912 = old B1; A1img 4,718,592 = old A1.
  // Overlays: Obuf->B1 slot; Vt->A1 slot (dead after gemm1); U/M/L->qkv slot.
  size_t off = 0;
  size_t off_B1 = off;  off += (size_t)N_TOK * K3 * 2;          // 12,582,912
  size_t off_A1 = off;  off += (size_t)K3 * K3 * 2;             //  4,718,592
  size_t off_A2 = off;  off += (size_t)512 * 512 * 2;           //    524,288
  size_t off_qkv = off; off += (size_t)N_TOK * K3 * 4;          // 25,165,824
  size_t off_Qp = off;  off += (size_t)HEADS * N_TOK * 128 * 2; //  8,388,608
  size_t off_Kp = off;  off += (size_t)HEADS * N_TOK * 128 * 2; //  8,388,608
  u16* B1img = (u16*)(ws + off_B1);  // 32*24*16KB
  u16* A1img = (u16*)(ws + off_A1);  // 12*24*16KB
  u16* A2 = (u16*)(ws + off_A2);
  float* qkv = (float*)(ws + off_qkv);
  u16* Qp = (u16*)(ws + off_Qp);
  u16* Kp = (u16*)(ws + off_Kp);
  u16* Vt = (u16*)(ws + off_A1);     // overlay A1 slot (4,194,304 <= 4,718,592)
  u16* Obuf = (u16*)(ws + off_B1);   // overlay B1 slot
  float* Uws = (float*)(ws + off_qkv);                       // 16,777,216
  float* Mws = (float*)(ws + off_qkv + 16777216);            //    262,144
  float* Lws = (float*)(ws + off_qkv + 16777216 + 262144);   //    262,144

  prep_w_kernel<<<(1536 * 512 + 255) / 256, 256, 0, stream>>>(w_qkv, A1img);
  prep_wout_kernel<<<(512 * 512 + 255) / 256, 256, 0, stream>>>(w_out, A2);
  prep_x_kernel<<<dim3(64, 8), 256, 0, stream>>>(x, B1img);
  // gemm1 (GLDS images): qkv[token][channel] = sum_k B1[token][k] * A1[channel][k]
  gemm_img_kernel<<<dim3(K3 / 128, N_TOK / 128), 256, 0, stream>>>(B1img, A1img, qkv, N_TOK, K3, K3);
  prep_qk_kernel<<<(HEADS * N_TOK * 64) / 256, 256, 0, stream>>>(qkv, Qp, Kp);
  prep_v_kernel<<<dim3(64, 8), 256, 0, stream>>>(qkv, Vt);
  attn_kernel<<<1024, 256, 0, stream>>>(Qp, Kp, Vt, Uws, Mws, Lws);
  reduce_kernel<<<(HEADS * N_TOK * 16) / 256, 256, 0, stream>>>(Uws, Mws, Lws, Obuf);
  // gemm2 (reg-staged): out[channel][token] = sum_k w_out[channel][k] * Obuf[token][k]
  gemm_nt_kernel<<<dim3(N_TOK / 128, 512 / 128), 256, 0, stream>>>(A2, Obuf, out, 512, N_TOK, 512);
}